// Round 14
// baseline (4605.051 us; speedup 1.0000x reference)
//
#include <hip/hip_runtime.h>
#include <hip/hip_bf16.h>

// LSTM surrogate: B=256, T=512, D=256, U=512, O=64.
// R14: dual-context blocks — deterministic anti-phase overlap.
// Grid 256 (1 block/CU). Block owns TWO batch-group contexts (bgA=bid&7,
// bgB=bgA+8) with the SAME unit-group -> weights shared in registers.
// Interleaved schedule hides each context's sync latency under the other's
// compute (R9-R13 showed work-rearrangement fails; phase-locked co-resident
// blocks don't overlap). All per-phase pieces are R12-proven verbatim.

#define Bb 256
#define Tt 512
#define Dd 256
#define Uu 512
#define Oo 64

typedef short bs8 __attribute__((ext_vector_type(8)));      // 8 bf16 (bits)
typedef float f32x4 __attribute__((ext_vector_type(4)));

__device__ __forceinline__ unsigned short f2bf(float f) {
  unsigned u = __float_as_uint(f);
  u += 0x7fffu + ((u >> 16) & 1u);                          // RNE
  return (unsigned short)(u >> 16);
}
__device__ __forceinline__ unsigned f2bf2(float lo, float hi) {
  union { __hip_bfloat162 b; unsigned u; } cv;
  cv.b = __float22bfloat162_rn(make_float2(lo, hi));        // v_cvt_pk_bf16_f32
  return cv.u;
}
__device__ __forceinline__ float bf2f(unsigned short s) {
  return __uint_as_float(((unsigned)s) << 16);
}
__device__ __forceinline__ float sigm(float v) { return 1.0f / (1.0f + __expf(-v)); }
__device__ __forceinline__ float tanhfast(float v) { return 2.0f / (1.0f + __expf(-2.0f * v)) - 1.0f; }

// z LDS: [16 rows][768 k] bf16, row stride 1536 B. XOR swizzle on 16B granules.
__device__ __forceinline__ int zbyte(int row, int k) {
  return (row * 1536 + k * 2) ^ ((row & 7) << 4);
}

// flags: group g, block i -> bar[(g*32 + i)*32]  (one 128B line per flag)
__global__ void rnn_init_bar(unsigned* bar) {
  for (int i = threadIdx.x; i < 16 * 32 * 32; i += 256)
    __hip_atomic_store(&bar[i], 0u, __ATOMIC_RELAXED, __HIP_MEMORY_SCOPE_AGENT);
}

__launch_bounds__(256, 1)
__global__ void rnn_lstm_kernel(const float* __restrict__ x, const float* __restrict__ Wx,
                                const float* __restrict__ Wh, const float* __restrict__ bias,
                                const float* __restrict__ Wd, const float* __restrict__ bd,
                                float* __restrict__ out, unsigned short* hbuf, unsigned* bar) {
  __shared__ __align__(16) char zsA[16 * 768 * 2];  // 24576 B
  __shared__ __align__(16) char zsB[16 * 768 * 2];  // 24576 B
  __shared__ float gatesA[4][16][17], gatesB[4][16][17];
  __shared__ float wdl[512][2];
  __shared__ float ypA[16][2][16], ypB[16][2][16];

  const int tid = threadIdx.x;
  const int lane = tid & 63;
  const int wid = tid >> 6;                         // wave 0..3 == gate id
  const int bid = blockIdx.x;
  const int bgA = bid & 7, bgB = bgA + 8;           // two groups, same XCD (%8 dispatch)
  const int ug = bid >> 3;                          // 0..31, shared by both contexts
  const int bbA = bgA * 16, bbB = bgB * 16;
  const int u_base = ug * 16;
  const int oc0 = ug * 2;
  unsigned* flA = bar + bgA * 32 * 32;
  unsigned* flB = bar + bgB * 32 * 32;

  // ---- weight slice as B-fragments (shared by both contexts) ----
  bs8 breg[24];
  {
    const int gc = wid * 512 + u_base + (lane & 15);
    const int kfr = (lane >> 4) * 8;
#pragma unroll
    for (int ks = 0; ks < 24; ++ks) {
      bs8 bb;
#pragma unroll
      for (int e = 0; e < 8; ++e) {
        int kg = ks * 32 + kfr + e;
        float w = (kg < 256) ? Wx[(size_t)kg * 2048 + gc]
                             : Wh[(size_t)(kg - 256) * 2048 + gc];
        bb[e] = (short)f2bf(w);
      }
      breg[ks] = bb;
    }
  }

  const int prow = tid & 15;
  const int usec = tid >> 4;                        // 0..15
  const int us4 = usec & 3;
  float bi[4], bff[4], bgg[4], boo[4];
  if (tid < 64) {
#pragma unroll
    for (int j = 0; j < 4; ++j) {
      int ugl = u_base + us4 * 4 + j;
      bi[j]  = bias[0 * 512 + ugl];
      bff[j] = bias[1 * 512 + ugl];
      bgg[j] = bias[2 * 512 + ugl];
      boo[j] = bias[3 * 512 + ugl];
    }
  }
  float cstA[4] = {0.f, 0.f, 0.f, 0.f};
  float cstB[4] = {0.f, 0.f, 0.f, 0.f};

  // ---- Wd slice to LDS ----
#pragma unroll
  for (int i = 0; i < 4; ++i) {
    int c = tid + i * 256;
    int u = c >> 1, oc = c & 1;
    wdl[u][oc] = Wd[(size_t)u * Oo + oc0 + oc];
  }

#define XSTAGE(ZS, BB, TIDX) do {                                              \
    int row_ = tid >> 4; int d0_ = (tid & 15) * 16;                            \
    const float* xp_ = x + ((size_t)((BB) + row_) * Tt + (TIDX)) * Dd + d0_;   \
    float4 v0_ = *(const float4*)xp_;  float4 v1_ = *(const float4*)(xp_ + 4); \
    float4 v2_ = *(const float4*)(xp_ + 8); float4 v3_ = *(const float4*)(xp_ + 12);\
    uint4 p0_, p1_;                                                            \
    p0_.x = f2bf2(v0_.x, v0_.y); p0_.y = f2bf2(v0_.z, v0_.w);                  \
    p0_.z = f2bf2(v1_.x, v1_.y); p0_.w = f2bf2(v1_.z, v1_.w);                  \
    p1_.x = f2bf2(v2_.x, v2_.y); p1_.y = f2bf2(v2_.z, v2_.w);                  \
    p1_.z = f2bf2(v3_.x, v3_.y); p1_.w = f2bf2(v3_.z, v3_.w);                  \
    *(uint4*)((ZS) + zbyte(row_, d0_)) = p0_;                                  \
    *(uint4*)((ZS) + zbyte(row_, d0_ + 8)) = p1_;                              \
  } while (0)

#define MFMA_PHASE(ZS, GATES) do {                                             \
    f32x4 a0_ = {0, 0, 0, 0}, a1_ = {0, 0, 0, 0};                              \
    _Pragma("unroll")                                                          \
    for (int ks = 0; ks < 24; ks += 2) {                                       \
      bs8 av0_ = *(const bs8*)((ZS) + zbyte(arow, ks * 32 + akf));             \
      bs8 av1_ = *(const bs8*)((ZS) + zbyte(arow, (ks + 1) * 32 + akf));       \
      a0_ = __builtin_amdgcn_mfma_f32_16x16x32_bf16(av0_, breg[ks], a0_, 0, 0, 0); \
      a1_ = __builtin_amdgcn_mfma_f32_16x16x32_bf16(av1_, breg[ks + 1], a1_, 0, 0, 0); \
    }                                                                          \
    a0_ += a1_;                                                                \
    { const int u16_ = lane & 15; const int rb_ = (lane >> 4) * 4;             \
      _Pragma("unroll")                                                        \
      for (int j = 0; j < 4; ++j) (GATES)[wid][rb_ + j][u16_] = a0_[j]; }      \
  } while (0)

#define PW_SWAP(GATES, CST, BB) do {                                           \
    float hv_[4];                                                              \
    _Pragma("unroll")                                                          \
    for (int j = 0; j < 4; ++j) {                                              \
      int u_ = us4 * 4 + j;                                                    \
      float gi_ = (GATES)[0][prow][u_] + bi[j];                                \
      float gf_ = (GATES)[1][prow][u_] + bff[j];                               \
      float gg_ = (GATES)[2][prow][u_] + bgg[j];                               \
      float go_ = (GATES)[3][prow][u_] + boo[j];                               \
      float iv_ = sigm(gi_), fv_ = sigm(gf_), gv_ = tanhfast(gg_), ov_ = sigm(go_); \
      float cn_ = fv_ * (CST)[j] + iv_ * gv_; (CST)[j] = cn_;                  \
      hv_[j] = ov_ * tanhfast(cn_);                                            \
    }                                                                          \
    unsigned long long hp_ = (unsigned long long)f2bf2(hv_[0], hv_[1]) |       \
        ((unsigned long long)f2bf2(hv_[2], hv_[3]) << 32);                     \
    unsigned long long* pp_ = (unsigned long long*)(hbuf + (size_t)(t & 1) * Bb * Uu \
        + (size_t)((BB) + prow) * Uu + u_base + us4 * 4);                      \
    unsigned long long old_ = __hip_atomic_exchange(pp_, hp_, __ATOMIC_RELAXED,\
        __HIP_MEMORY_SCOPE_AGENT);                                             \
    asm volatile("" :: "v"(old_));                                             \
  } while (0)

#define YDECODE(ZS, YP) do {                                                   \
    float s0_ = 0.f, s1_ = 0.f;                                                \
    _Pragma("unroll")                                                          \
    for (int c8 = 0; c8 < 4; ++c8) {                                           \
      int k_ = 256 + usec * 32 + c8 * 8;                                       \
      bs8 hv_ = *(const bs8*)((ZS) + zbyte(prow, k_));                         \
      _Pragma("unroll")                                                        \
      for (int e = 0; e < 8; ++e) {                                            \
        float hf_ = bf2f((unsigned short)hv_[e]);                              \
        int u_ = usec * 32 + c8 * 8 + e;                                       \
        s0_ += hf_ * wdl[u_][0]; s1_ += hf_ * wdl[u_][1];                      \
      }                                                                        \
    }                                                                          \
    (YP)[prow][0][usec] = s0_; (YP)[prow][1][usec] = s1_;                      \
  } while (0)

#define FLAGPUB(FL) do {                                                       \
    unsigned oldf_ = __hip_atomic_exchange(&(FL)[ug * 32], (unsigned)(t + 1),  \
        __ATOMIC_RELAXED, __HIP_MEMORY_SCOPE_AGENT);                           \
    asm volatile("" :: "v"(oldf_));                                            \
  } while (0)

#define POLL(FL) do {                                                          \
    for (;;) {                                                                 \
      unsigned v_ = __hip_atomic_load(&(FL)[(lane & 31) * 32],                 \
          __ATOMIC_RELAXED, __HIP_MEMORY_SCOPE_AGENT);                         \
      if (!__any((int)(v_ < (unsigned)(t + 1)))) break;                        \
      __builtin_amdgcn_s_sleep(2);                                             \
    }                                                                          \
  } while (0)

#define HLOAD(ZS, BB) do {                                                     \
    const unsigned short* hs_ = hbuf + (size_t)(t & 1) * Bb * Uu;              \
    int idx_ = (tid < 64) ? tid : tid - 64;  /* waves 0,2,3 -> 0..191 */       \
    for (int c_ = idx_; c_ < 1024; c_ += 192) {                                \
      int row_ = c_ >> 6; int u0_ = (c_ & 63) * 8;                             \
      const unsigned long long* p_ = (const unsigned long long*)               \
          (hs_ + (size_t)((BB) + row_) * Uu + u0_);                            \
      unsigned long long q0_ = __hip_atomic_load(p_, __ATOMIC_RELAXED, __HIP_MEMORY_SCOPE_AGENT); \
      unsigned long long q1_ = __hip_atomic_load(p_ + 1, __ATOMIC_RELAXED, __HIP_MEMORY_SCOPE_AGENT); \
      *(unsigned long long*)((ZS) + zbyte(row_, 256 + u0_)) = q0_;             \
      *(unsigned long long*)((ZS) + zbyte(row_, 256 + u0_ + 4)) = q1_;         \
    }                                                                          \
  } while (0)

#define YSTORE(YP, BB, TT) do {                                                \
    int b_ = lane >> 1, oc_ = lane & 1;                                        \
    float s_ = bd[oc0 + oc_];                                                  \
    _Pragma("unroll")                                                          \
    for (int q_ = 0; q_ < 16; ++q_) s_ += (YP)[b_][oc_][q_];                   \
    out[((size_t)((BB) + b_) * Tt + (TT)) * Oo + oc0 + oc_] = s_;              \
  } while (0)

  // ---- prologue: stage x_0 both contexts, zero h both ----
  XSTAGE(zsA, bbA, 0);
  XSTAGE(zsB, bbB, 0);
#pragma unroll
  for (int i = 0; i < 4; ++i) {
    int c = tid + i * 256;
    int row = c >> 6;
    int u0 = (c & 63) * 8;
    bs8 zz = {0, 0, 0, 0, 0, 0, 0, 0};
    *(bs8*)(zsA + zbyte(row, 256 + u0)) = zz;
    *(bs8*)(zsB + zbyte(row, 256 + u0)) = zz;
  }
  __syncthreads();

  const int arow = lane & 15;
  const int akf = (lane >> 4) * 8;

  for (int t = 0; t < Tt; ++t) {
    // ---- P1: A.mfma ----
    MFMA_PHASE(zsA, gatesA);
    __syncthreads();                                   // bar1
    // ---- P2: A.pointwise+swap (w0) ; A.window (all) ----
    if (tid < 64) PW_SWAP(gatesA, cstA, bbA);
    if (t + 1 < Tt) XSTAGE(zsA, bbA, t + 1);
    if (t > 0) YDECODE(zsA, ypA);
    __syncthreads();                                   // bar2 (drains A swaps)
    if (tid == 0) FLAGPUB(flA);
    // ---- P3: B.mfma (covers A flag->poll gap) ----
    MFMA_PHASE(zsB, gatesB);
    __syncthreads();                                   // bar3
    // ---- P4: B.pointwise+swap (w0) ; B.window (all) ; w1: A.poll ----
    if (tid < 64) PW_SWAP(gatesB, cstB, bbB);
    if (t + 1 < Tt) XSTAGE(zsB, bbB, t + 1);
    if (t > 0) YDECODE(zsB, ypB);
    if (wid == 1) POLL(flA);
    __builtin_amdgcn_sched_barrier(0);
    __syncthreads();                                   // bar4 (drains B swaps)
    if (tid == 0) FLAGPUB(flB);
    // ---- P5: A.hload (waves 0,2,3) ; w1: B.poll + A.ystore ----
    if (wid != 1) {
      HLOAD(zsA, bbA);
    } else {
      POLL(flB);
      if (t > 0 && lane < 32) YSTORE(ypA, bbA, t - 1);
    }
    __builtin_amdgcn_sched_barrier(0);
    __syncthreads();                                   // bar5
    // ---- P6: B.hload (waves 0,2,3) ; w1: B.ystore ----
    if (wid != 1) {
      HLOAD(zsB, bbB);
    } else {
      if (t > 0 && lane < 32) YSTORE(ypB, bbB, t - 1);
    }
    __syncthreads();                                   // bar6
  }

  // ---- epilogue: y_{T-1} for both contexts ----
  YDECODE(zsA, ypA);
  __syncthreads();
  if (tid < 64 && lane < 32) YSTORE(ypA, bbA, Tt - 1);
  YDECODE(zsB, ypB);
  __syncthreads();
  if (tid < 64 && lane < 32) YSTORE(ypB, bbB, Tt - 1);
}

extern "C" void kernel_launch(void* const* d_in, const int* in_sizes, int n_in,
                              void* d_out, int out_size, void* d_ws, size_t ws_size,
                              hipStream_t stream) {
  const float* x  = (const float*)d_in[0];
  const float* Wx = (const float*)d_in[1];
  const float* Wh = (const float*)d_in[2];
  const float* bs = (const float*)d_in[3];
  const float* Wd = (const float*)d_in[4];
  const float* bd = (const float*)d_in[5];
  float* out = (float*)d_out;

  unsigned short* hbuf = (unsigned short*)d_ws;                       // 2*256*512 bf16 = 512 KiB
  unsigned* bar = (unsigned*)((char*)d_ws + (size_t)2 * Bb * Uu * 2); // 16g * 32 flags * 128B

  rnn_init_bar<<<1, 256, 0, stream>>>(bar);
  rnn_lstm_kernel<<<dim3(256), dim3(256), 0, stream>>>(x, Wx, Wh, bs, Wd, bd, out, hbuf, bar);
}

// Round 16
// 2949.078 us; speedup vs baseline: 1.5615x; 1.5615x over previous
//
#include <hip/hip_runtime.h>

// LSTM surrogate: B=256, T=512, D=256, U=512, O=64.
// R16 = R12 verbatim (proven 2424us) + flag exchange moved to intra-XCD L2
// using ONLY returning-atomic primitives (R15's sc0-load poll hung: sc0 loads
// fill/hit L1 -> permanently stale; RMW results come from the L2 execution
// point, immune to cache semantics).
//  - group := physical XCD (s_getreg XCC_ID) + per-XCD counter; dynamic-LDS pad
//    caps occupancy at 2 blocks/CU -> exactly 64 blocks/XCD -> every (group,
//    slot) assigned exactly once -> no deadlock by construction.
//  - flag publish: workgroup-scope swap (executes at shared L2, ~250cy)
//  - poll: fetch_add(hidden 0) workgroup scope (fresh L2 read each iter)
//  - h legs unchanged: agent swap (L3) / agent loads (L3) — proven.

#define Bb 256
#define Tt 512
#define Dd 256
#define Uu 512
#define Oo 64

typedef short bs8 __attribute__((ext_vector_type(8)));      // 8 bf16 (bits)
typedef float f32x4 __attribute__((ext_vector_type(4)));

__device__ __forceinline__ unsigned short f2bf(float f) {
  unsigned u = __float_as_uint(f);
  u += 0x7fffu + ((u >> 16) & 1u);                          // RNE
  return (unsigned short)(u >> 16);
}
__device__ __forceinline__ float bf2f(unsigned short s) {
  return __uint_as_float(((unsigned)s) << 16);
}
__device__ __forceinline__ float sigm(float v) { return 1.0f / (1.0f + __expf(-v)); }
__device__ __forceinline__ float tanhfast(float v) { return 2.0f / (1.0f + __expf(-2.0f * v)) - 1.0f; }

// z LDS: [16 rows][768 k] bf16, row stride 1536 B. XOR swizzle on 16B granules.
__device__ __forceinline__ int zbyte(int row, int k) {
  return (row * 1536 + k * 2) ^ ((row & 7) << 4);
}

// bar layout: [0, 16384): flags — group g, slot s at (g*32+s)*32 (own 128B line)
//             [16384, 16640): per-XCD slot counters, stride 32
__global__ void rnn_init_bar(unsigned* bar) {
  for (int i = threadIdx.x; i < 16 * 32 * 32 + 8 * 32; i += 256)
    __hip_atomic_store(&bar[i], 0u, __ATOMIC_RELAXED, __HIP_MEMORY_SCOPE_AGENT);
}

__launch_bounds__(256, 2)
__global__ void rnn_lstm_kernel(const float* __restrict__ x, const float* __restrict__ Wx,
                                const float* __restrict__ Wh, const float* __restrict__ bias,
                                const float* __restrict__ Wd, const float* __restrict__ bd,
                                float* __restrict__ out, unsigned short* hbuf, unsigned* bar) {
  __shared__ __align__(16) char zs[16 * 768 * 2];   // 24576 B
  __shared__ float gates[4][16][17];                // [gate][row][unit], pad
  __shared__ float wdl[512][2];                     // Wd slice for this block's 2 out cols
  __shared__ float ypart[16][2][16];                // [row][oc][usec]
  __shared__ unsigned slotsh;
  // + 24576 B dynamic pad (launch arg) -> 59.9KB/block -> hard cap 2 blocks/CU

  const int tid = threadIdx.x;
  const int lane = tid & 63;
  const int wid = tid >> 6;                         // wave 0..3 == gate id

  unsigned xcd;
  asm("s_getreg_b32 %0, hwreg(HW_REG_XCC_ID)" : "=s"(xcd));
  xcd &= 7u;
  if (tid == 0) {
    unsigned* cnts = bar + 16 * 32 * 32;
    slotsh = __hip_atomic_fetch_add(&cnts[xcd * 32], 1u, __ATOMIC_RELAXED,
                                    __HIP_MEMORY_SCOPE_AGENT);  // L3, once/block
  }
  __syncthreads();
  // exactly 64 blocks/XCD (2/CU x 32 CU, LDS-capped) -> s in 0..63 unique
  const unsigned s = slotsh & 63u;
  const int bg = (int)xcd + 8 * (int)(s & 1u);      // group 0..15, members share L2
  const int ug = (int)(s >> 1) & 31;                // slot 0..31, unique per group
  const int b_base = bg * 16;
  const int u_base = ug * 16;
  const int oc0 = ug * 2;

  unsigned* fl = bar + bg * 32 * 32;  // 32 flags, each on its own 128B line

  // ---- weight slice as B-fragments: wave w = gate w; col=lane&15, k=(lane>>4)*8+e ----
  bs8 breg[24];
  {
    const int gc = wid * 512 + u_base + (lane & 15);
    const int kfr = (lane >> 4) * 8;
#pragma unroll
    for (int ks = 0; ks < 24; ++ks) {
      bs8 bb;
#pragma unroll
      for (int e = 0; e < 8; ++e) {
        int kg = ks * 32 + kfr + e;
        float w = (kg < 256) ? Wx[(size_t)kg * 2048 + gc]
                             : Wh[(size_t)(kg - 256) * 2048 + gc];
        bb[e] = (short)f2bf(w);
      }
      breg[ks] = bb;
    }
  }

  // pointwise ownership (tid<64): row = tid&15, us4 = tid>>4 (0..3), units us4*4+{0..3}
  const int prow = tid & 15;
  const int usec = tid >> 4;                        // 0..15 (y-decode sections of 32 units)
  const int us4 = usec & 3;
  float bi[4], bff[4], bgg[4], boo[4];
  if (tid < 64) {
#pragma unroll
    for (int j = 0; j < 4; ++j) {
      int ugl = u_base + us4 * 4 + j;
      bi[j]  = bias[0 * 512 + ugl];
      bff[j] = bias[1 * 512 + ugl];
      bgg[j] = bias[2 * 512 + ugl];
      boo[j] = bias[3 * 512 + ugl];
    }
  }
  float cst[4] = {0.f, 0.f, 0.f, 0.f};

  union U16 { unsigned long long q[2]; bs8 v; };

  // ---- prologue: Wd slice to LDS, stage x_0, zero h-region ----
#pragma unroll
  for (int i = 0; i < 4; ++i) {
    int c = tid + i * 256;
    int u = c >> 1, oc = c & 1;
    wdl[u][oc] = Wd[(size_t)u * Oo + oc0 + oc];
  }
  {
    int row = tid >> 4;
    int d0 = (tid & 15) * 16;
    const float* xp = x + ((size_t)(b_base + row) * Tt + 0) * Dd + d0;
    float4 v0 = *(const float4*)xp;
    float4 v1 = *(const float4*)(xp + 4);
    float4 v2 = *(const float4*)(xp + 8);
    float4 v3 = *(const float4*)(xp + 12);
    bs8 p0, p1;
    p0[0] = (short)f2bf(v0.x); p0[1] = (short)f2bf(v0.y);
    p0[2] = (short)f2bf(v0.z); p0[3] = (short)f2bf(v0.w);
    p0[4] = (short)f2bf(v1.x); p0[5] = (short)f2bf(v1.y);
    p0[6] = (short)f2bf(v1.z); p0[7] = (short)f2bf(v1.w);
    p1[0] = (short)f2bf(v2.x); p1[1] = (short)f2bf(v2.y);
    p1[2] = (short)f2bf(v2.z); p1[3] = (short)f2bf(v2.w);
    p1[4] = (short)f2bf(v3.x); p1[5] = (short)f2bf(v3.y);
    p1[6] = (short)f2bf(v3.z); p1[7] = (short)f2bf(v3.w);
    *(bs8*)(zs + zbyte(row, d0)) = p0;
    *(bs8*)(zs + zbyte(row, d0 + 8)) = p1;
  }
#pragma unroll
  for (int i = 0; i < 4; ++i) {
    int c = tid + i * 256;
    int row = c >> 6;
    int u0 = (c & 63) * 8;
    bs8 zz = {0, 0, 0, 0, 0, 0, 0, 0};
    *(bs8*)(zs + zbyte(row, 256 + u0)) = zz;
  }
  __syncthreads();

  for (int t = 0; t < Tt; ++t) {
    // ---- gates MFMA: each wave computes its gate's [16 rows x 16 units], K=768 ----
    f32x4 acc0 = {0, 0, 0, 0}, acc1 = {0, 0, 0, 0};
    {
      const int arow = lane & 15;
      const int akf = (lane >> 4) * 8;
#pragma unroll
      for (int ks = 0; ks < 24; ks += 2) {
        bs8 av0 = *(const bs8*)(zs + zbyte(arow, ks * 32 + akf));
        bs8 av1 = *(const bs8*)(zs + zbyte(arow, (ks + 1) * 32 + akf));
        acc0 = __builtin_amdgcn_mfma_f32_16x16x32_bf16(av0, breg[ks], acc0, 0, 0, 0);
        acc1 = __builtin_amdgcn_mfma_f32_16x16x32_bf16(av1, breg[ks + 1], acc1, 0, 0, 0);
      }
      acc0 += acc1;
    }
    // C/D (HW-verified): col = lane&15, row = (lane>>4)*4 + reg
    {
      const int u16 = lane & 15;
      const int rb = (lane >> 4) * 4;
#pragma unroll
      for (int j = 0; j < 4; ++j) gates[wid][rb + j][u16] = acc0[j];
    }
    __syncthreads();

    // ---- pointwise LSTM cell (tid<64); h published via AGENT swap_x2 (L3) ----
    if (tid < 64) {
      unsigned long long hpack = 0ull;
#pragma unroll
      for (int j = 0; j < 4; ++j) {
        int u = us4 * 4 + j;
        float gi = gates[0][prow][u] + bi[j];
        float gf = gates[1][prow][u] + bff[j];
        float gg = gates[2][prow][u] + bgg[j];
        float go = gates[3][prow][u] + boo[j];
        float iv = sigm(gi), fv = sigm(gf), gv = tanhfast(gg), ov = sigm(go);
        float cn = fv * cst[j] + iv * gv;
        cst[j] = cn;
        float hv = ov * tanhfast(cn);
        hpack |= ((unsigned long long)f2bf(hv)) << (16 * j);
      }
      unsigned long long* hp =
          (unsigned long long*)(hbuf + (size_t)(t & 1) * Bb * Uu +
                                (size_t)(b_base + prow) * Uu + u_base + us4 * 4);
      unsigned long long old = __hip_atomic_exchange(hp, hpack, __ATOMIC_RELAXED,
                                                     __HIP_MEMORY_SCOPE_AGENT);
      asm volatile("" :: "v"(old));   // keep the returning (executes-at-L3) form
    }
    // barrier drains each wave's vmcnt: all h-swaps have EXECUTED AT L3 here.
    __syncthreads();
    if (tid == 0) {
      // flag at intra-XCD L2 (workgroup-scope RMW executes at the shared L2);
      // h is already at L3 before this issues -> ordering safe.
      unsigned oldf = __hip_atomic_exchange(&fl[ug * 32], (unsigned)(t + 1),
                                            __ATOMIC_RELAXED, __HIP_MEMORY_SCOPE_WORKGROUP);
      asm volatile("" :: "v"(oldf));
    }

    // ---- barrier window: stage x_{t+1} (x-region of zs is dead) ----
    if (t + 1 < Tt) {
      int row = tid >> 4;
      int d0 = (tid & 15) * 16;
      const float* xp = x + ((size_t)(b_base + row) * Tt + (t + 1)) * Dd + d0;
      float4 v0 = *(const float4*)xp;
      float4 v1 = *(const float4*)(xp + 4);
      float4 v2 = *(const float4*)(xp + 8);
      float4 v3 = *(const float4*)(xp + 12);
      bs8 p0, p1;
      p0[0] = (short)f2bf(v0.x); p0[1] = (short)f2bf(v0.y);
      p0[2] = (short)f2bf(v0.z); p0[3] = (short)f2bf(v0.w);
      p0[4] = (short)f2bf(v1.x); p0[5] = (short)f2bf(v1.y);
      p0[6] = (short)f2bf(v1.z); p0[7] = (short)f2bf(v1.w);
      p1[0] = (short)f2bf(v2.x); p1[1] = (short)f2bf(v2.y);
      p1[2] = (short)f2bf(v2.z); p1[3] = (short)f2bf(v2.w);
      p1[4] = (short)f2bf(v3.x); p1[5] = (short)f2bf(v3.y);
      p1[6] = (short)f2bf(v3.z); p1[7] = (short)f2bf(v3.w);
      *(bs8*)(zs + zbyte(row, d0)) = p0;
      *(bs8*)(zs + zbyte(row, d0 + 8)) = p1;
    }

    // ---- barrier window: y_{t-1} partials from LDS h copy ----
    if (t > 0) {
      float s0 = 0.f, s1 = 0.f;
#pragma unroll
      for (int c8 = 0; c8 < 4; ++c8) {
        int k = 256 + usec * 32 + c8 * 8;
        bs8 hv = *(const bs8*)(zs + zbyte(prow, k));
#pragma unroll
        for (int e = 0; e < 8; ++e) {
          float hf = bf2f((unsigned short)hv[e]);
          int u = usec * 32 + c8 * 8 + e;
          s0 += hf * wdl[u][0];
          s1 += hf * wdl[u][1];
        }
      }
      ypart[prow][0][usec] = s0;
      ypart[prow][1][usec] = s1;
    }
    __syncthreads();
    // y reduce on wave0; poll on wave1 via returning-RMW at L2 (cache-immune)
    if (t > 0 && tid < 32) {
      int b = tid >> 1, oc = tid & 1;
      float s2 = bd[oc0 + oc];
#pragma unroll
      for (int q = 0; q < 16; ++q) s2 += ypart[b][oc][q];
      out[((size_t)(b_base + b) * Tt + (t - 1)) * Oo + oc0 + oc] = s2;
    }
    if (wid == 1) {
      unsigned zero = 0;
      asm volatile("" : "+v"(zero));  // hide 0 so the RMW can't be weakened
      for (;;) {
        unsigned v = __hip_atomic_fetch_add(&fl[(lane & 31) * 32], zero,
                                            __ATOMIC_RELAXED, __HIP_MEMORY_SCOPE_WORKGROUP);
        if (!__any((int)(v < (unsigned)(t + 1)))) break;
        __builtin_amdgcn_s_sleep(2);
      }
    }
    __builtin_amdgcn_sched_barrier(0);
    __syncthreads();

    // ---- stage h_t from hbuf[t&1] (agent loads: L3-coherent, proven) ----
    {
      const unsigned short* hsrc = hbuf + (size_t)(t & 1) * Bb * Uu;
#pragma unroll
      for (int i = 0; i < 4; ++i) {
        int c = tid + i * 256;
        int row = c >> 6;
        int u0 = (c & 63) * 8;
        const unsigned long long* p =
            (const unsigned long long*)(hsrc + (size_t)(b_base + row) * Uu + u0);
        U16 uu;
        uu.q[0] = __hip_atomic_load(p, __ATOMIC_RELAXED, __HIP_MEMORY_SCOPE_AGENT);
        uu.q[1] = __hip_atomic_load(p + 1, __ATOMIC_RELAXED, __HIP_MEMORY_SCOPE_AGENT);
        *(bs8*)(zs + zbyte(row, 256 + u0)) = uu.v;
      }
    }
    __syncthreads();
  }

  // ---- epilogue: y_{T-1} (h_{T-1} staged by final iteration) ----
  {
    float s0 = 0.f, s1 = 0.f;
#pragma unroll
    for (int c8 = 0; c8 < 4; ++c8) {
      int k = 256 + usec * 32 + c8 * 8;
      bs8 hv = *(const bs8*)(zs + zbyte(prow, k));
#pragma unroll
      for (int e = 0; e < 8; ++e) {
        float hf = bf2f((unsigned short)hv[e]);
        int u = usec * 32 + c8 * 8 + e;
        s0 += hf * wdl[u][0];
        s1 += hf * wdl[u][1];
      }
    }
    ypart[prow][0][usec] = s0;
    ypart[prow][1][usec] = s1;
    __syncthreads();
    if (tid < 32) {
      int b = tid >> 1, oc = tid & 1;
      float s2 = bd[oc0 + oc];
#pragma unroll
      for (int q = 0; q < 16; ++q) s2 += ypart[b][oc][q];
      out[((size_t)(b_base + b) * Tt + (Tt - 1)) * Oo + oc0 + oc] = s2;
    }
  }
}

extern "C" void kernel_launch(void* const* d_in, const int* in_sizes, int n_in,
                              void* d_out, int out_size, void* d_ws, size_t ws_size,
                              hipStream_t stream) {
  const float* x  = (const float*)d_in[0];
  const float* Wx = (const float*)d_in[1];
  const float* Wh = (const float*)d_in[2];
  const float* bs = (const float*)d_in[3];
  const float* Wd = (const float*)d_in[4];
  const float* bd = (const float*)d_in[5];
  float* out = (float*)d_out;

  unsigned short* hbuf = (unsigned short*)d_ws;                       // 512 KiB
  unsigned* bar = (unsigned*)((char*)d_ws + (size_t)2 * Bb * Uu * 2); // flags+counters 65 KiB

  rnn_init_bar<<<1, 256, 0, stream>>>(bar);
  // 24576 B dynamic LDS -> 59.9 KB/block -> hard cap 2 blocks/CU ->
  // 512 blocks place exactly 2/CU -> exactly 64 blocks (= groups xcd, xcd+8,
  // 32 slots each) per XCD. Flag exchange stays inside one L2.
  rnn_lstm_kernel<<<dim3(512), dim3(256), 24576, stream>>>(x, Wx, Wh, bs, Wd, bd,
                                                           out, hbuf, bar);
}